// Round 3
// baseline (103.765 us; speedup 1.0000x reference)
//
#include <hip/hip_runtime.h>

#define AS1 __attribute__((address_space(1)))
#define AS3 __attribute__((address_space(3)))

typedef unsigned short u16;
typedef __bf16 bf16x8 __attribute__((ext_vector_type(8)));
typedef float f32x4 __attribute__((ext_vector_type(4)));
typedef unsigned short u16x8 __attribute__((ext_vector_type(8)));

// ws layout (20 MB + 128 B):
//   A:   [4][512][1024] bf16(u16) @ 0      (4 MB)   A[seg][b][i] = b_seg(x[b][i])
//   P:   [8][512][1024] f32       @ 4 MB   (16 MB)  split-K partials
//   ctr: [32] int                 @ 20 MB           per-output-tile arrival counters

__device__ __forceinline__ u16 f2bf(float f) {
    union { float f; unsigned int u; } v;
    v.f = f;
    unsigned int u = v.u;
    u += 0x7fffu + ((u >> 16) & 1u);   // RNE
    return (u16)(u >> 16);
}

// A-prep only (x -> Bernstein-weighted bf16) + zero the tile counters.
__global__ __launch_bounds__(256) void prep_a_kernel(
    const float* __restrict__ x, u16* __restrict__ A, int* __restrict__ ctr)
{
    const int bid = blockIdx.x;
    const int tid = threadIdx.x;
    if (bid == 0 && tid < 32) ctr[tid] = 0;

    const int idx = (bid * 256 + tid) * 4;   // [0, 524288)
    float4 v = *(const float4*)(x + idx);
    float vv[4] = {v.x, v.y, v.z, v.w};
    u16 q[4][4];
    #pragma unroll
    for (int j = 0; j < 4; ++j) {
        float xx = vv[j];
        float t = fminf(fabsf(xx), 1.0f);
        float s = 1.0f - t;
        q[0][j] = f2bf(s * s * s * xx);
        q[1][j] = f2bf(3.0f * s * s * t * xx);
        q[2][j] = f2bf(3.0f * s * t * t * xx);
        q[3][j] = f2bf(t * t * t * xx);
    }
    #pragma unroll
    for (int seg = 0; seg < 4; ++seg) {
        ushort4 o; o.x = q[seg][0]; o.y = q[seg][1]; o.z = q[seg][2]; o.w = q[seg][3];
        *(ushort4*)(A + seg * 524288 + idx) = o;
    }
}

__device__ __forceinline__ void load16(const u16* g, u16* l) {
    __builtin_amdgcn_global_load_lds((const AS1 unsigned int*)g,
                                     (AS3 unsigned int*)l, 16, 0, 0);
}

// 128x128 tile, split-K=8, 512 threads (8 waves of 64x32).
// A staged via global_load_lds (pre-swizzled source, linear LDS dest).
// W staged from cp f32: linear coalesced loads -> reg cvt -> swizzled ds_write_b128.
// LDS mapping both tiles: chunk (row, s) holds global (row, s ^ (row&7)).
// Tail: deterministic last-arriver reduction of the 8 K-slice partials.
__global__ __launch_bounds__(512) void gemm_kernel(
    const u16* __restrict__ A,
    const float* __restrict__ cp0, const float* __restrict__ cp1,
    const float* __restrict__ cp2, const float* __restrict__ cp3,
    float* __restrict__ P, float* __restrict__ out, int* __restrict__ ctr)
{
    __shared__ u16 lsA[2][128 * 64];
    __shared__ u16 lsB[2][128 * 64];
    __shared__ int s_last;

    const int tid  = threadIdx.x;
    const int lane = tid & 63;
    const int wid  = tid >> 6;

    const int bid  = blockIdx.x;          // 0..255
    const int nb   = bid & 7;             // N-block -> XCD affinity
    const int mb   = (bid >> 3) & 3;      // M-block
    const int kz   = bid >> 5;            // K-slice 0..7
    const int seg  = kz >> 1;
    const int kbase = (kz & 1) * 512;
    const int brow = mb * 128;
    const int bcol = nb * 128;

    const u16* Ag = A + seg * 524288 + brow * 1024 + kbase;
    const float* cps[4] = {cp0, cp1, cp2, cp3};
    const float* Wg = cps[seg] + bcol * 1024 + kbase;

    // A staging: 1024 chunks of 16B; chunk c: row=c>>3, sub=c&7; source pre-swizzled
    int goffA[2], loffA[2];
    #pragma unroll
    for (int j = 0; j < 2; ++j) {
        const int c   = tid + j * 512;
        const int row = c >> 3;
        goffA[j] = row * 1024 + ((c & 7) ^ (row & 7)) * 8;
        loffA[j] = c * 8;
    }
    // W staging: linear global (8 consecutive f32 per chunk), swizzled LDS dest
    int wgoff[2], wloff[2];
    #pragma unroll
    for (int j = 0; j < 2; ++j) {
        const int c   = tid + j * 512;
        const int row = c >> 3;
        const int sub = c & 7;
        wgoff[j] = row * 1024 + sub * 8;                 // f32 elements
        wloff[j] = (row * 8 + (sub ^ (row & 7))) * 8;    // u16 elements
    }

    // wave sub-tile: 2(M) x 4(N); each wave 64x32
    const int wr = (wid >> 2) * 64;
    const int wc = (wid & 3) * 32;
    const int fr = lane & 15;
    int ofs[2];
    ofs[0] = (((lane >> 4)    ) ^ (lane & 7)) * 16;
    ofs[1] = (((lane >> 4) + 4) ^ (lane & 7)) * 16;

    f32x4 acc[4][2] = {};

    // ---- prologue: stage tile 0 ----
    #pragma unroll
    for (int j = 0; j < 2; ++j)
        load16(Ag + goffA[j], &lsA[0][loffA[j]]);
    #pragma unroll
    for (int j = 0; j < 2; ++j) {
        float4 p0 = *(const float4*)(Wg + wgoff[j]);
        float4 p1 = *(const float4*)(Wg + wgoff[j] + 4);
        u16x8 w;
        w[0] = f2bf(p0.x); w[1] = f2bf(p0.y); w[2] = f2bf(p0.z); w[3] = f2bf(p0.w);
        w[4] = f2bf(p1.x); w[5] = f2bf(p1.y); w[6] = f2bf(p1.z); w[7] = f2bf(p1.w);
        *(u16x8*)&lsB[0][wloff[j]] = w;
    }
    __syncthreads();

    for (int kt = 0; kt < 8; ++kt) {
        const int buf = kt & 1;
        float4 wp[2][2];
        if (kt < 7) {
            const int k0 = (kt + 1) * 64;
            // issue next W loads early (latency hides under MFMA)
            #pragma unroll
            for (int j = 0; j < 2; ++j) {
                wp[j][0] = *(const float4*)(Wg + k0 + wgoff[j]);
                wp[j][1] = *(const float4*)(Wg + k0 + wgoff[j] + 4);
            }
            // next A tile direct-to-LDS
            #pragma unroll
            for (int j = 0; j < 2; ++j)
                load16(Ag + k0 + goffA[j], &lsA[buf ^ 1][loffA[j]]);
        }

        const char* bA = (const char*)lsA[buf];
        const char* bB = (const char*)lsB[buf];
        #pragma unroll
        for (int kk = 0; kk < 2; ++kk) {
            bf16x8 a[4], b[2];
            #pragma unroll
            for (int m = 0; m < 4; ++m)
                a[m] = *(const bf16x8*)(bA + (wr + m * 16 + fr) * 128 + ofs[kk]);
            #pragma unroll
            for (int n = 0; n < 2; ++n)
                b[n] = *(const bf16x8*)(bB + (wc + n * 16 + fr) * 128 + ofs[kk]);
            #pragma unroll
            for (int m = 0; m < 4; ++m)
                #pragma unroll
                for (int n = 0; n < 2; ++n)
                    acc[m][n] = __builtin_amdgcn_mfma_f32_16x16x32_bf16(
                        a[m], b[n], acc[m][n], 0, 0, 0);
        }

        if (kt < 7) {
            // convert + write next W tile (waits on wp loads here, after MFMA)
            #pragma unroll
            for (int j = 0; j < 2; ++j) {
                u16x8 w;
                w[0] = f2bf(wp[j][0].x); w[1] = f2bf(wp[j][0].y);
                w[2] = f2bf(wp[j][0].z); w[3] = f2bf(wp[j][0].w);
                w[4] = f2bf(wp[j][1].x); w[5] = f2bf(wp[j][1].y);
                w[6] = f2bf(wp[j][1].z); w[7] = f2bf(wp[j][1].w);
                *(u16x8*)&lsB[buf ^ 1][wloff[j]] = w;
            }
        }
        __syncthreads();
    }

    // ---- epilogue: partial store (C/D layout: col=lane&15, row=(lane>>4)*4+j) ----
    float* Pk = P + kz * 524288;
    const int cr0 = brow + wr + (lane >> 4) * 4;
    const int cc0 = bcol + wc + fr;
    #pragma unroll
    for (int m = 0; m < 4; ++m)
        #pragma unroll
        for (int n = 0; n < 2; ++n)
            #pragma unroll
            for (int j = 0; j < 4; ++j)
                Pk[(cr0 + m * 16 + j) * 1024 + cc0 + n * 16] = acc[m][n][j];

    // ---- deterministic last-arriver reduction ----
    __threadfence();
    __syncthreads();
    if (tid == 0) {
        int old = __hip_atomic_fetch_add(&ctr[mb * 8 + nb], 1,
                                         __ATOMIC_ACQ_REL, __HIP_MEMORY_SCOPE_AGENT);
        s_last = (old == 7);
    }
    __syncthreads();
    if (!s_last) return;
    __threadfence();

    // reduce this 128x128 tile: fixed kz order 0..7 -> bitwise deterministic
    #pragma unroll
    for (int j = 0; j < 8; ++j) {
        const int id = tid + j * 512;        // 4096 float4s per tile
        const int r  = id >> 5;
        const int q  = (id & 31) * 4;
        const int off = (brow + r) * 1024 + bcol + q;
        float4 s = *(const float4*)(P + off);
        #pragma unroll
        for (int z = 1; z < 8; ++z) {
            float4 v = *(const float4*)(P + z * 524288 + off);
            s.x += v.x; s.y += v.y; s.z += v.z; s.w += v.w;
        }
        *(float4*)(out + off) = s;
    }
    if (tid == 0)
        __hip_atomic_store(&ctr[mb * 8 + nb], 0,
                           __ATOMIC_RELAXED, __HIP_MEMORY_SCOPE_AGENT);
}

extern "C" void kernel_launch(void* const* d_in, const int* in_sizes, int n_in,
                              void* d_out, int out_size, void* d_ws, size_t ws_size,
                              hipStream_t stream)
{
    const float* x   = (const float*)d_in[0];
    const float* cp0 = (const float*)d_in[1];
    const float* cp1 = (const float*)d_in[2];
    const float* cp2 = (const float*)d_in[3];
    const float* cp3 = (const float*)d_in[4];

    u16*   A   = (u16*)d_ws;
    float* P   = (float*)((char*)d_ws + (4u << 20));
    int*   ctr = (int*)((char*)d_ws + (20u << 20));
    float* out = (float*)d_out;

    prep_a_kernel<<<512, 256, 0, stream>>>(x, A, ctr);
    gemm_kernel<<<256, 512, 0, stream>>>(A, cp0, cp1, cp2, cp3, P, out, ctr);
}

// Round 4
// 30.027 us; speedup vs baseline: 3.4557x; 3.4557x over previous
//
#include <hip/hip_runtime.h>

#define AS1 __attribute__((address_space(1)))
#define AS3 __attribute__((address_space(3)))

typedef unsigned short u16;
typedef __bf16 bf16x8 __attribute__((ext_vector_type(8)));
typedef float f32x4 __attribute__((ext_vector_type(4)));
typedef unsigned short u16x8 __attribute__((ext_vector_type(8)));

// ws layout (20 MB):
//   A: [4][512][1024] bf16(u16) @ 0      (4 MB)   A[seg][b][i] = b_seg(x[b][i])
//   P: [8][512][1024] f32       @ 4 MB   (16 MB)  split-K partials

__device__ __forceinline__ u16 f2bf(float f) {
    union { float f; unsigned int u; } v;
    v.f = f;
    unsigned int u = v.u;
    u += 0x7fffu + ((u >> 16) & 1u);   // RNE
    return (u16)(u >> 16);
}

// A-prep: x -> Bernstein-weighted bf16, 4 segments. 6 MB traffic.
__global__ __launch_bounds__(256) void prep_a_kernel(
    const float* __restrict__ x, u16* __restrict__ A)
{
    const int idx = (blockIdx.x * 256 + threadIdx.x) * 4;   // [0, 524288)
    float4 v = *(const float4*)(x + idx);
    float vv[4] = {v.x, v.y, v.z, v.w};
    u16 q[4][4];
    #pragma unroll
    for (int j = 0; j < 4; ++j) {
        float xx = vv[j];
        float t = fminf(fabsf(xx), 1.0f);
        float s = 1.0f - t;
        q[0][j] = f2bf(s * s * s * xx);
        q[1][j] = f2bf(3.0f * s * s * t * xx);
        q[2][j] = f2bf(3.0f * s * t * t * xx);
        q[3][j] = f2bf(t * t * t * xx);
    }
    #pragma unroll
    for (int seg = 0; seg < 4; ++seg) {
        ushort4 o; o.x = q[seg][0]; o.y = q[seg][1]; o.z = q[seg][2]; o.w = q[seg][3];
        *(ushort4*)(A + seg * 524288 + idx) = o;
    }
}

__device__ __forceinline__ void load16(const u16* g, u16* l) {
    __builtin_amdgcn_global_load_lds((const AS1 unsigned int*)g,
                                     (AS3 unsigned int*)l, 16, 0, 0);
}

// 128x128 tile, split-K=8 (seg-halves of 512), 512 threads (8 waves of 64x32).
// A staged via global_load_lds (pre-swizzled source, linear LDS dest).
// W staged from cp f32: early coalesced loads -> reg cvt -> swizzled ds_write_b128.
// LDS mapping both tiles: 16B chunk (row, s) holds global chunk (row, s ^ (row&7)).
// NO device-scope fences/atomics (round-3 lesson: they collapse L2 for the chip).
__global__ __launch_bounds__(512) void gemm_kernel(
    const u16* __restrict__ A,
    const float* __restrict__ cp0, const float* __restrict__ cp1,
    const float* __restrict__ cp2, const float* __restrict__ cp3,
    float* __restrict__ P)
{
    __shared__ u16 lsA[2][128 * 64];
    __shared__ u16 lsB[2][128 * 64];

    const int tid  = threadIdx.x;
    const int lane = tid & 63;
    const int wid  = tid >> 6;

    const int bid  = blockIdx.x;          // 0..255
    const int nb   = bid & 7;             // N-block -> XCD affinity (bid % 8)
    const int mb   = (bid >> 3) & 3;      // M-block
    const int kz   = bid >> 5;            // K-slice 0..7
    const int seg  = kz >> 1;
    const int kbase = (kz & 1) * 512;
    const int brow = mb * 128;
    const int bcol = nb * 128;

    const u16* Ag = A + seg * 524288 + brow * 1024 + kbase;
    const float* cps[4] = {cp0, cp1, cp2, cp3};
    const float* Wg = cps[seg] + bcol * 1024 + kbase;

    // A staging: 1024 chunks of 16B; chunk c: row=c>>3, sub=c&7; source pre-swizzled
    int goffA[2], loffA[2];
    #pragma unroll
    for (int j = 0; j < 2; ++j) {
        const int c   = tid + j * 512;
        const int row = c >> 3;
        goffA[j] = row * 1024 + ((c & 7) ^ (row & 7)) * 8;
        loffA[j] = c * 8;
    }
    // W staging: linear global (8 consecutive f32 per chunk), swizzled LDS dest
    int wgoff[2], wloff[2];
    #pragma unroll
    for (int j = 0; j < 2; ++j) {
        const int c   = tid + j * 512;
        const int row = c >> 3;
        const int sub = c & 7;
        wgoff[j] = row * 1024 + sub * 8;                 // f32 elements
        wloff[j] = (row * 8 + (sub ^ (row & 7))) * 8;    // u16 elements
    }

    // wave sub-tile: 2(M) x 4(N); each wave 64x32
    const int wr = (wid >> 2) * 64;
    const int wc = (wid & 3) * 32;
    const int fr = lane & 15;
    int ofs[2];
    ofs[0] = (((lane >> 4)    ) ^ (lane & 7)) * 16;
    ofs[1] = (((lane >> 4) + 4) ^ (lane & 7)) * 16;

    f32x4 acc[4][2] = {};

    // ---- prologue: stage tile 0 ----
    #pragma unroll
    for (int j = 0; j < 2; ++j)
        load16(Ag + goffA[j], &lsA[0][loffA[j]]);
    #pragma unroll
    for (int j = 0; j < 2; ++j) {
        float4 p0 = *(const float4*)(Wg + wgoff[j]);
        float4 p1 = *(const float4*)(Wg + wgoff[j] + 4);
        u16x8 w;
        w[0] = f2bf(p0.x); w[1] = f2bf(p0.y); w[2] = f2bf(p0.z); w[3] = f2bf(p0.w);
        w[4] = f2bf(p1.x); w[5] = f2bf(p1.y); w[6] = f2bf(p1.z); w[7] = f2bf(p1.w);
        *(u16x8*)&lsB[0][wloff[j]] = w;
    }
    __syncthreads();

    for (int kt = 0; kt < 8; ++kt) {
        const int buf = kt & 1;
        float4 wp[2][2];
        if (kt < 7) {
            const int k0 = (kt + 1) * 64;
            // issue next W loads early (latency hides under MFMA)
            #pragma unroll
            for (int j = 0; j < 2; ++j) {
                wp[j][0] = *(const float4*)(Wg + k0 + wgoff[j]);
                wp[j][1] = *(const float4*)(Wg + k0 + wgoff[j] + 4);
            }
            // next A tile direct-to-LDS
            #pragma unroll
            for (int j = 0; j < 2; ++j)
                load16(Ag + k0 + goffA[j], &lsA[buf ^ 1][loffA[j]]);
        }

        const char* bA = (const char*)lsA[buf];
        const char* bB = (const char*)lsB[buf];
        #pragma unroll
        for (int kk = 0; kk < 2; ++kk) {
            bf16x8 a[4], b[2];
            #pragma unroll
            for (int m = 0; m < 4; ++m)
                a[m] = *(const bf16x8*)(bA + (wr + m * 16 + fr) * 128 + ofs[kk]);
            #pragma unroll
            for (int n = 0; n < 2; ++n)
                b[n] = *(const bf16x8*)(bB + (wc + n * 16 + fr) * 128 + ofs[kk]);
            #pragma unroll
            for (int m = 0; m < 4; ++m)
                #pragma unroll
                for (int n = 0; n < 2; ++n)
                    acc[m][n] = __builtin_amdgcn_mfma_f32_16x16x32_bf16(
                        a[m], b[n], acc[m][n], 0, 0, 0);
        }

        if (kt < 7) {
            // convert + write next W tile (vmcnt wait lands here, after MFMA)
            #pragma unroll
            for (int j = 0; j < 2; ++j) {
                u16x8 w;
                w[0] = f2bf(wp[j][0].x); w[1] = f2bf(wp[j][0].y);
                w[2] = f2bf(wp[j][0].z); w[3] = f2bf(wp[j][0].w);
                w[4] = f2bf(wp[j][1].x); w[5] = f2bf(wp[j][1].y);
                w[6] = f2bf(wp[j][1].z); w[7] = f2bf(wp[j][1].w);
                *(u16x8*)&lsB[buf ^ 1][wloff[j]] = w;
            }
        }
        __syncthreads();
    }

    // ---- epilogue: partial store (C/D layout: col=lane&15, row=(lane>>4)*4+j) ----
    float* Pk = P + kz * 524288;
    const int cr0 = brow + wr + (lane >> 4) * 4;
    const int cc0 = bcol + wc + fr;
    #pragma unroll
    for (int m = 0; m < 4; ++m)
        #pragma unroll
        for (int n = 0; n < 2; ++n)
            #pragma unroll
            for (int j = 0; j < 4; ++j)
                Pk[(cr0 + m * 16 + j) * 1024 + cc0 + n * 16] = acc[m][n][j];
}

// Fixed-order 8-slice sum: bitwise deterministic.
__global__ __launch_bounds__(256) void reduce_kernel(
    const float* __restrict__ P, float* __restrict__ out)
{
    const int idx = (blockIdx.x * 256 + threadIdx.x) * 4;
    float4 s = *(const float4*)(P + idx);
    #pragma unroll
    for (int z = 1; z < 8; ++z) {
        float4 v = *(const float4*)(P + z * 524288 + idx);
        s.x += v.x; s.y += v.y; s.z += v.z; s.w += v.w;
    }
    *(float4*)(out + idx) = s;
}

extern "C" void kernel_launch(void* const* d_in, const int* in_sizes, int n_in,
                              void* d_out, int out_size, void* d_ws, size_t ws_size,
                              hipStream_t stream)
{
    const float* x   = (const float*)d_in[0];
    const float* cp0 = (const float*)d_in[1];
    const float* cp1 = (const float*)d_in[2];
    const float* cp2 = (const float*)d_in[3];
    const float* cp3 = (const float*)d_in[4];

    u16*   A   = (u16*)d_ws;
    float* P   = (float*)((char*)d_ws + (4u << 20));
    float* out = (float*)d_out;

    prep_a_kernel<<<512, 256, 0, stream>>>(x, A);
    gemm_kernel<<<256, 512, 0, stream>>>(A, cp0, cp1, cp2, cp3, P);
    reduce_kernel<<<512, 256, 0, stream>>>(P, out);
}

// Round 5
// 29.993 us; speedup vs baseline: 3.4597x; 1.0011x over previous
//
#include <hip/hip_runtime.h>

#define AS1 __attribute__((address_space(1)))
#define AS3 __attribute__((address_space(3)))

typedef unsigned short u16;
typedef __bf16 bf16x8 __attribute__((ext_vector_type(8)));
typedef float f32x4 __attribute__((ext_vector_type(4)));

// ws layout (28 MB):
//   A: [4][512][1024]  bf16(u16) @ 0      (4 MB)   A[seg][b][i] = b_seg(x[b][i])
//   W: [4][1024][1024] bf16(u16) @ 4 MB   (8 MB)   W[seg][o][i] = bf16(cp_seg[o][i])
//   P: [8][512][1024]  f32       @ 12 MB  (16 MB)  split-K partials

__device__ __forceinline__ u16 f2bf(float f) {
    union { float f; unsigned int u; } v;
    v.f = f;
    unsigned int u = v.u;
    u += 0x7fffu + ((u >> 16) & 1u);   // RNE
    return (u16)(u >> 16);
}

__global__ __launch_bounds__(256) void prep_kernel(
    const float* __restrict__ x,
    const float* __restrict__ cp0, const float* __restrict__ cp1,
    const float* __restrict__ cp2, const float* __restrict__ cp3,
    u16* __restrict__ A, u16* __restrict__ W)
{
    const int bid = blockIdx.x;
    const int tid = threadIdx.x;
    if (bid < 1024) {
        const int idx = (bid * 256 + tid) * 4;            // [0, 1048576)
        const float* cps[4] = {cp0, cp1, cp2, cp3};
        #pragma unroll
        for (int seg = 0; seg < 4; ++seg) {
            float4 v = *(const float4*)(cps[seg] + idx);
            ushort4 o;
            o.x = f2bf(v.x); o.y = f2bf(v.y); o.z = f2bf(v.z); o.w = f2bf(v.w);
            *(ushort4*)(W + seg * 1048576 + idx) = o;
        }
    } else {
        const int idx = ((bid - 1024) * 256 + tid) * 4;   // [0, 524288)
        float4 v = *(const float4*)(x + idx);
        float vv[4] = {v.x, v.y, v.z, v.w};
        u16 q[4][4];
        #pragma unroll
        for (int j = 0; j < 4; ++j) {
            float xx = vv[j];
            float t = fminf(fabsf(xx), 1.0f);
            float s = 1.0f - t;
            q[0][j] = f2bf(s * s * s * xx);
            q[1][j] = f2bf(3.0f * s * s * t * xx);
            q[2][j] = f2bf(3.0f * s * t * t * xx);
            q[3][j] = f2bf(t * t * t * xx);
        }
        #pragma unroll
        for (int seg = 0; seg < 4; ++seg) {
            ushort4 o; o.x = q[seg][0]; o.y = q[seg][1]; o.z = q[seg][2]; o.w = q[seg][3];
            *(ushort4*)(A + seg * 524288 + idx) = o;
        }
    }
}

__device__ __forceinline__ void load16(const u16* g, u16* l) {
    __builtin_amdgcn_global_load_lds((const AS1 unsigned int*)g,
                                     (AS3 unsigned int*)l, 16, 0, 0);
}

// 64x128 tile, split-K=8 (seg-halves of 512), 256 threads (4 waves, each 64x32).
// Grid 512 = 2 WGs/CU: co-resident WG covers the other's barrier drain (m114).
// LDS [rows][64] bf16 XOR-swizzled: 16B chunk (row,s) holds global (row, s^(row&7)),
// staged with pre-swizzled global source + linear global_load_lds dest.
__global__ __launch_bounds__(256) void gemm_kernel(
    const u16* __restrict__ A, const u16* __restrict__ W,
    float* __restrict__ P)
{
    __shared__ u16 lsA[2][64 * 64];
    __shared__ u16 lsB[2][128 * 64];

    const int tid  = threadIdx.x;
    const int lane = tid & 63;
    const int wid  = tid >> 6;

    const int bid  = blockIdx.x;          // 0..511
    const int nb   = bid & 7;             // N-block -> XCD affinity (bid % 8)
    const int mb   = (bid >> 3) & 7;      // M-block (8 x 64 rows)
    const int kz   = bid >> 6;            // K-slice 0..7
    const int seg  = kz >> 1;
    const int kbase = (kz & 1) * 512;
    const int brow = mb * 64;
    const int bcol = nb * 128;

    const u16* Ag = A + seg * 524288  + brow * 1024 + kbase;
    const u16* Wg = W + seg * 1048576 + bcol * 1024 + kbase;

    // A staging: 512 chunks of 16B (64 rows x 8 subs); 2 per thread
    int goffA[2], loffA[2];
    #pragma unroll
    for (int j = 0; j < 2; ++j) {
        const int c   = tid + j * 256;
        const int row = c >> 3;
        goffA[j] = row * 1024 + ((c & 7) ^ (row & 7)) * 8;
        loffA[j] = c * 8;
    }
    // W staging: 1024 chunks (128 rows x 8 subs); 4 per thread
    int goffW[4], loffW[4];
    #pragma unroll
    for (int j = 0; j < 4; ++j) {
        const int c   = tid + j * 256;
        const int row = c >> 3;
        goffW[j] = row * 1024 + ((c & 7) ^ (row & 7)) * 8;
        loffW[j] = c * 8;
    }

    // wave sub-tile: full 64 M rows x 32 N cols per wave (wave wid -> cols wid*32)
    const int wc = wid * 32;
    const int fr = lane & 15;
    int ofs[2];
    ofs[0] = (((lane >> 4)    ) ^ (lane & 7)) * 16;
    ofs[1] = (((lane >> 4) + 4) ^ (lane & 7)) * 16;

    f32x4 acc[4][2] = {};

    // ---- prologue: stage tile 0 ----
    #pragma unroll
    for (int j = 0; j < 2; ++j)
        load16(Ag + goffA[j], &lsA[0][loffA[j]]);
    #pragma unroll
    for (int j = 0; j < 4; ++j)
        load16(Wg + goffW[j], &lsB[0][loffW[j]]);
    __syncthreads();

    for (int kt = 0; kt < 8; ++kt) {
        const int buf = kt & 1;
        if (kt < 7) {
            const int k0 = (kt + 1) * 64;
            #pragma unroll
            for (int j = 0; j < 2; ++j)
                load16(Ag + k0 + goffA[j], &lsA[buf ^ 1][loffA[j]]);
            #pragma unroll
            for (int j = 0; j < 4; ++j)
                load16(Wg + k0 + goffW[j], &lsB[buf ^ 1][loffW[j]]);
        }
        const char* bA = (const char*)lsA[buf];
        const char* bB = (const char*)lsB[buf];
        #pragma unroll
        for (int kk = 0; kk < 2; ++kk) {
            bf16x8 a[4], b[2];
            #pragma unroll
            for (int m = 0; m < 4; ++m)
                a[m] = *(const bf16x8*)(bA + (m * 16 + fr) * 128 + ofs[kk]);
            #pragma unroll
            for (int n = 0; n < 2; ++n)
                b[n] = *(const bf16x8*)(bB + (wc + n * 16 + fr) * 128 + ofs[kk]);
            #pragma unroll
            for (int m = 0; m < 4; ++m)
                #pragma unroll
                for (int n = 0; n < 2; ++n)
                    acc[m][n] = __builtin_amdgcn_mfma_f32_16x16x32_bf16(
                        a[m], b[n], acc[m][n], 0, 0, 0);
        }
        __syncthreads();   // vmcnt(0) drain; co-resident WG computes meanwhile
    }

    // ---- epilogue: C/D layout col = lane&15, row = (lane>>4)*4 + j ----
    float* Pk = P + kz * 524288;
    const int cr0 = brow + (lane >> 4) * 4;
    const int cc0 = bcol + wc + fr;
    #pragma unroll
    for (int m = 0; m < 4; ++m)
        #pragma unroll
        for (int n = 0; n < 2; ++n)
            #pragma unroll
            for (int j = 0; j < 4; ++j)
                Pk[(cr0 + m * 16 + j) * 1024 + cc0 + n * 16] = acc[m][n][j];
}

// Fixed-order 8-slice sum (bitwise deterministic). Block bid&7 == gemm writer's
// XCD key (nb) -> P reads served by the local XCD L2.
__global__ __launch_bounds__(256) void reduce_kernel(
    const float* __restrict__ P, float* __restrict__ out)
{
    const int nb = blockIdx.x & 7;
    const int mb = blockIdx.x >> 3;      // 0..7
    const int tid = threadIdx.x;
    #pragma unroll
    for (int j = 0; j < 8; ++j) {
        const int id = tid + j * 256;          // 2048 float4 per 64x128 tile
        const int r  = id >> 5;
        const int c4 = (id & 31) * 4;
        const int off = (mb * 64 + r) * 1024 + nb * 128 + c4;
        float4 s = *(const float4*)(P + off);
        #pragma unroll
        for (int z = 1; z < 8; ++z) {
            float4 v = *(const float4*)(P + z * 524288 + off);
            s.x += v.x; s.y += v.y; s.z += v.z; s.w += v.w;
        }
        *(float4*)(out + off) = s;
    }
}

extern "C" void kernel_launch(void* const* d_in, const int* in_sizes, int n_in,
                              void* d_out, int out_size, void* d_ws, size_t ws_size,
                              hipStream_t stream)
{
    const float* x   = (const float*)d_in[0];
    const float* cp0 = (const float*)d_in[1];
    const float* cp1 = (const float*)d_in[2];
    const float* cp2 = (const float*)d_in[3];
    const float* cp3 = (const float*)d_in[4];

    u16*   A   = (u16*)d_ws;
    u16*   Wb  = (u16*)((char*)d_ws + (4u << 20));
    float* P   = (float*)((char*)d_ws + (12u << 20));
    float* out = (float*)d_out;

    prep_kernel<<<1536, 256, 0, stream>>>(x, cp0, cp1, cp2, cp3, A, Wb);
    gemm_kernel<<<512, 256, 0, stream>>>(A, Wb, P);
    reduce_kernel<<<64, 256, 0, stream>>>(P, out);
}